// Round 1
// baseline (3999.017 us; speedup 1.0000x reference)
//
#include <hip/hip_runtime.h>
#include <math.h>

#define CD 256

__device__ __forceinline__ float sigmoidf_(float x) { return 1.0f / (1.0f + expf(-x)); }
__device__ __forceinline__ float geluf_(float x) { return 0.5f * x * (1.0f + erff(x * 0.70710678118654752f)); }

// ---------------------------------------------------------------------------
// Generic Y[N,256] = alpha*(X[N,256] @ W[256,256]) + bias, fp32 tiled.
// 64x64 tile per block, 256 threads, 4x4 per thread, LDS-staged with X^T.
// ---------------------------------------------------------------------------
__global__ __launch_bounds__(256) void gemm_bias(
    const float* __restrict__ X, const float* __restrict__ W,
    const float* __restrict__ bias, float* __restrict__ Y,
    int N, float alpha)
{
    __shared__ float Xs[64][68];  // [k][row]  (transposed for contiguous float4 reads)
    __shared__ float Ws[64][68];  // [k][col]
    const int tid  = threadIdx.x;
    const int row0 = blockIdx.x * 64;
    const int col0 = blockIdx.y * 64;
    const int tx = tid & 15;
    const int ty = tid >> 4;
    float acc[4][4] = {};

    for (int k0 = 0; k0 < CD; k0 += 64) {
#pragma unroll
        for (int m = 0; m < 4; ++m) {
            int flat = tid + m * 256;      // float4-granular id, 0..1023
            int r  = flat >> 4;            // 0..63
            int kq = flat & 15;            // 0..15
            int gr = row0 + r; gr = (gr < N) ? gr : (N - 1);
            float4 v = *(const float4*)(X + (size_t)gr * CD + k0 + kq * 4);
            Xs[kq * 4 + 0][r] = v.x;
            Xs[kq * 4 + 1][r] = v.y;
            Xs[kq * 4 + 2][r] = v.z;
            Xs[kq * 4 + 3][r] = v.w;
        }
#pragma unroll
        for (int m = 0; m < 4; ++m) {
            int flat = tid + m * 256;
            int k  = flat >> 4;
            int cq = flat & 15;
            float4 v = *(const float4*)(W + (size_t)(k0 + k) * CD + col0 + cq * 4);
            *(float4*)&Ws[k][cq * 4] = v;
        }
        __syncthreads();
#pragma unroll
        for (int k = 0; k < 64; ++k) {
            float4 a = *(const float4*)&Xs[k][ty * 4];
            float4 b = *(const float4*)&Ws[k][tx * 4];
            acc[0][0] += a.x * b.x; acc[0][1] += a.x * b.y; acc[0][2] += a.x * b.z; acc[0][3] += a.x * b.w;
            acc[1][0] += a.y * b.x; acc[1][1] += a.y * b.y; acc[1][2] += a.y * b.z; acc[1][3] += a.y * b.w;
            acc[2][0] += a.z * b.x; acc[2][1] += a.z * b.y; acc[2][2] += a.z * b.z; acc[2][3] += a.z * b.w;
            acc[3][0] += a.w * b.x; acc[3][1] += a.w * b.y; acc[3][2] += a.w * b.z; acc[3][3] += a.w * b.w;
        }
        __syncthreads();
    }
#pragma unroll
    for (int i = 0; i < 4; ++i) {
        int row = row0 + ty * 4 + i;
        if (row < N) {
            int col = col0 + tx * 4;
            float4 bb = *(const float4*)(bias + col);
            float4 o;
            o.x = alpha * acc[i][0] + bb.x;
            o.y = alpha * acc[i][1] + bb.y;
            o.z = alpha * acc[i][2] + bb.z;
            o.w = alpha * acc[i][3] + bb.w;
            *(float4*)(Y + (size_t)row * CD + col) = o;
        }
    }
}

// ---------------------------------------------------------------------------
// ce gate: G[r,:] = sigmoid( gelu(ea[ebase+r,:3] @ W1 + b1) @ W2 + b2 )
// Same GEMM structure; the A-tile (H = gelu(...)) is computed on the fly.
// ---------------------------------------------------------------------------
__global__ __launch_bounds__(256) void gate_ce_gemm(
    const float* __restrict__ EA, const float* __restrict__ W1,
    const float* __restrict__ b1, const float* __restrict__ W2,
    const float* __restrict__ b2, float* __restrict__ G,
    int ebase, int count)
{
    __shared__ float Hs[64][68];
    __shared__ float Ws[64][68];
    const int tid  = threadIdx.x;
    const int row0 = blockIdx.x * 64;
    const int col0 = blockIdx.y * 64;
    const int tx = tid & 15;
    const int ty = tid >> 4;
    float acc[4][4] = {};

    for (int k0 = 0; k0 < CD; k0 += 64) {
#pragma unroll
        for (int m = 0; m < 4; ++m) {
            int flat = tid + m * 256;
            int r  = flat >> 4;
            int kq = flat & 15;
            int rr = row0 + r; rr = (rr < count) ? rr : (count - 1);
            size_t eo = (size_t)(ebase + rr) * 3;
            float a0 = EA[eo], a1 = EA[eo + 1], a2 = EA[eo + 2];
            int kk = k0 + kq * 4;
            float4 w0 = *(const float4*)(W1 + kk);
            float4 w1 = *(const float4*)(W1 + CD + kk);
            float4 w2 = *(const float4*)(W1 + 2 * CD + kk);
            float4 bb = *(const float4*)(b1 + kk);
            Hs[kq * 4 + 0][r] = geluf_(a0 * w0.x + a1 * w1.x + a2 * w2.x + bb.x);
            Hs[kq * 4 + 1][r] = geluf_(a0 * w0.y + a1 * w1.y + a2 * w2.y + bb.y);
            Hs[kq * 4 + 2][r] = geluf_(a0 * w0.z + a1 * w1.z + a2 * w2.z + bb.z);
            Hs[kq * 4 + 3][r] = geluf_(a0 * w0.w + a1 * w1.w + a2 * w2.w + bb.w);
        }
#pragma unroll
        for (int m = 0; m < 4; ++m) {
            int flat = tid + m * 256;
            int k  = flat >> 4;
            int cq = flat & 15;
            float4 v = *(const float4*)(W2 + (size_t)(k0 + k) * CD + col0 + cq * 4);
            *(float4*)&Ws[k][cq * 4] = v;
        }
        __syncthreads();
#pragma unroll
        for (int k = 0; k < 64; ++k) {
            float4 a = *(const float4*)&Hs[k][ty * 4];
            float4 b = *(const float4*)&Ws[k][tx * 4];
            acc[0][0] += a.x * b.x; acc[0][1] += a.x * b.y; acc[0][2] += a.x * b.z; acc[0][3] += a.x * b.w;
            acc[1][0] += a.y * b.x; acc[1][1] += a.y * b.y; acc[1][2] += a.y * b.z; acc[1][3] += a.y * b.w;
            acc[2][0] += a.z * b.x; acc[2][1] += a.z * b.y; acc[2][2] += a.z * b.z; acc[2][3] += a.z * b.w;
            acc[3][0] += a.w * b.x; acc[3][1] += a.w * b.y; acc[3][2] += a.w * b.z; acc[3][3] += a.w * b.w;
        }
        __syncthreads();
    }
#pragma unroll
    for (int i = 0; i < 4; ++i) {
        int row = row0 + ty * 4 + i;
        if (row < count) {
            int col = col0 + tx * 4;
            float4 bb = *(const float4*)(b2 + col);
            float4 o;
            o.x = sigmoidf_(acc[i][0] + bb.x);
            o.y = sigmoidf_(acc[i][1] + bb.y);
            o.z = sigmoidf_(acc[i][2] + bb.z);
            o.w = sigmoidf_(acc[i][3] + bb.w);
            *(float4*)(G + (size_t)row * CD + col) = o;
        }
    }
}

// ---------------------------------------------------------------------------
// Gate lookup tables (cg: 50 combos, cp: 3 phenos)
// ---------------------------------------------------------------------------
__global__ void gate_cg_table_k(const float* __restrict__ embA, const float* __restrict__ embB,
                                const float* __restrict__ Wg, const float* __restrict__ bg,
                                float* __restrict__ tab)
{
    int combo = blockIdx.x;           // a*5 + b, a<10, b<5
    int a = combo / 5, b = combo % 5;
    int j = threadIdx.x;
    float s = bg[j];
    for (int k = 0; k < 32; ++k) s += embA[a * 32 + k] * Wg[k * CD + j];
    for (int k = 0; k < 32; ++k) s += embB[b * 32 + k] * Wg[(32 + k) * CD + j];
    tab[(size_t)combo * CD + j] = sigmoidf_(s);
}

__global__ void gate_cp_table_k(const float* __restrict__ embP, const float* __restrict__ Wg,
                                const float* __restrict__ bg, float* __restrict__ tab)
{
    int p = blockIdx.x;
    int j = threadIdx.x;
    float s = bg[j];
    for (int k = 0; k < 32; ++k) s += embP[p * 32 + k] * Wg[k * CD + j];
    tab[(size_t)p * CD + j] = sigmoidf_(s);
}

// ---------------------------------------------------------------------------
// Edge aggregation: one wave per edge. msg = Psrc[si] + Pdst[di], gated,
// atomically accumulated into aggr[di]. (Attention weight == 0.25 is folded
// into the downstream output-GEMM alpha, so no attention math here.)
// MODE: 0 = no gate (gg), 1 = cg table (a*5+b), 2 = cp table, 3 = per-edge buf
// ---------------------------------------------------------------------------
template <int MODE>
__global__ __launch_bounds__(256) void edge_aggr(
    const float* __restrict__ Psrc, const float* __restrict__ Pdst,
    const int* __restrict__ ei, int Etotal,
    const float* __restrict__ gate, const int* __restrict__ eai,
    float* __restrict__ aggr, int e_base, int e_count)
{
    int wid = blockIdx.x * 4 + (threadIdx.x >> 6);
    if (wid >= e_count) return;
    int lane = threadIdx.x & 63;
    int e = e_base + wid;
    int si = ei[e];
    int di = ei[Etotal + e];

    float4 m = *(const float4*)(Psrc + (size_t)si * CD + lane * 4);
    float4 d = *(const float4*)(Pdst + (size_t)di * CD + lane * 4);
    m.x += d.x; m.y += d.y; m.z += d.z; m.w += d.w;

    if (MODE == 1) {
        int a = eai[2 * e], b = eai[2 * e + 1];
        float4 g = *(const float4*)(gate + (size_t)(a * 5 + b) * CD + lane * 4);
        m.x *= g.x; m.y *= g.y; m.z *= g.z; m.w *= g.w;
    } else if (MODE == 2) {
        int p = eai[e];
        float4 g = *(const float4*)(gate + (size_t)p * CD + lane * 4);
        m.x *= g.x; m.y *= g.y; m.z *= g.z; m.w *= g.w;
    } else if (MODE == 3) {
        float4 g = *(const float4*)(gate + (size_t)(e - e_base) * CD + lane * 4);
        m.x *= g.x; m.y *= g.y; m.z *= g.z; m.w *= g.w;
    }

    float* ap = aggr + (size_t)di * CD + lane * 4;
    atomicAdd(ap + 0, m.x);
    atomicAdd(ap + 1, m.y);
    atomicAdd(ap + 2, m.z);
    atomicAdd(ap + 3, m.w);
}

// ---------------------------------------------------------------------------
extern "C" void kernel_launch(void* const* d_in, const int* in_sizes, int n_in,
                              void* d_out, int out_size, void* d_ws, size_t ws_size,
                              hipStream_t stream)
{
    const float* x_chem = (const float*)d_in[0];
    const float* x_gene = (const float*)d_in[1];
    const float* x_go   = (const float*)d_in[2];
    const float* x_pw   = (const float*)d_in[3];
    const int*   ei_cg  = (const int*)d_in[4];
    const int*   ei_cp  = (const int*)d_in[5];
    const int*   ei_ce  = (const int*)d_in[6];
    const int*   ei_gg  = (const int*)d_in[7];
    const int*   ea_cg  = (const int*)d_in[8];
    const int*   ea_cp  = (const int*)d_in[9];
    const float* ea_ce  = (const float*)d_in[10];

    const float* W_src_cg = (const float*)d_in[11];
    const float* b_src_cg = (const float*)d_in[12];
    const float* W_dst_cg = (const float*)d_in[13];
    const float* b_dst_cg = (const float*)d_in[14];
    const float* W_src_cp = (const float*)d_in[16];
    const float* b_src_cp = (const float*)d_in[17];
    const float* W_dst_cp = (const float*)d_in[18];
    const float* b_dst_cp = (const float*)d_in[19];
    const float* W_src_ce = (const float*)d_in[21];
    const float* b_src_ce = (const float*)d_in[22];
    const float* W_dst_ce = (const float*)d_in[23];
    const float* b_dst_ce = (const float*)d_in[24];
    const float* W_src_gg = (const float*)d_in[26];
    const float* b_src_gg = (const float*)d_in[27];
    const float* W_dst_gg = (const float*)d_in[28];
    const float* b_dst_gg = (const float*)d_in[29];

    const float* emb_at   = (const float*)d_in[31];
    const float* emb_as   = (const float*)d_in[32];
    const float* W_gate_cg = (const float*)d_in[33];
    const float* b_gate_cg = (const float*)d_in[34];
    const float* emb_ph   = (const float*)d_in[35];
    const float* W_gate_cp = (const float*)d_in[36];
    const float* b_gate_cp = (const float*)d_in[37];
    const float* W_gate1_ce = (const float*)d_in[38];
    const float* b_gate1_ce = (const float*)d_in[39];
    const float* W_gate2_ce = (const float*)d_in[40];
    const float* b_gate2_ce = (const float*)d_in[41];
    const float* W_out_gene = (const float*)d_in[42];
    const float* b_out_gene = (const float*)d_in[43];
    const float* W_out_go   = (const float*)d_in[44];
    const float* b_out_go   = (const float*)d_in[45];
    const float* W_out_pw   = (const float*)d_in[46];
    const float* b_out_pw   = (const float*)d_in[47];

    const int Nc  = in_sizes[0] / CD;
    const int Ng  = in_sizes[1] / CD;
    const int Ngo = in_sizes[2] / CD;
    const int Np  = in_sizes[3] / CD;
    const int E   = in_sizes[4] / 2;

    // ---- workspace layout (floats) ----
    float* ws = (float*)d_ws;
    size_t off = 0;
    float* aggr_gene = ws + off; off += (size_t)Ng  * CD;   // cg + gg accumulate here
    float* aggr_go   = ws + off; off += (size_t)Ngo * CD;
    float* aggr_pw   = ws + off; off += (size_t)Np  * CD;
    const size_t aggr_floats = off;
    int maxSrc = (Nc > Ng) ? Nc : Ng;
    int maxDst = Ng; if (Ngo > maxDst) maxDst = Ngo; if (Np > maxDst) maxDst = Np;
    float* proj_src = ws + off; off += (size_t)maxSrc * CD;
    float* proj_dst = ws + off; off += (size_t)maxDst * CD;
    float* gtab_cg  = ws + off; off += 50 * CD;
    float* gtab_cp  = ws + off; off += 3 * CD;
    // remaining space -> ce gate chunk buffer
    float* gate_ce  = ws + off;
    size_t remaining = ws_size / 4 - off;
    int CHUNK = (int)(remaining / CD);
    if (CHUNK > 25000) CHUNK = 25000;
    if (CHUNK < 1) CHUNK = 1;

    float* out_gene = (float*)d_out + (size_t)Nc * CD;
    float* out_go   = out_gene + (size_t)Ng * CD;
    float* out_pw   = out_go + (size_t)Ngo * CD;

    // 1) passthrough copy: x_chemical -> out[0]
    hipMemcpyAsync(d_out, x_chem, (size_t)Nc * CD * sizeof(float),
                   hipMemcpyDeviceToDevice, stream);

    // 2) zero the aggregation buffers (ws is poisoned each call)
    hipMemsetAsync(ws, 0, aggr_floats * sizeof(float), stream);

    // 3) gate tables
    gate_cg_table_k<<<50, 256, 0, stream>>>(emb_at, emb_as, W_gate_cg, b_gate_cg, gtab_cg);
    gate_cp_table_k<<<3, 256, 0, stream>>>(emb_ph, W_gate_cp, b_gate_cp, gtab_cp);

    auto gemm = [&](const float* X, const float* W, const float* b, float* Y, int N, float alpha) {
        dim3 grid((N + 63) / 64, 4);
        gemm_bias<<<grid, 256, 0, stream>>>(X, W, b, Y, N, alpha);
    };

    // 4) cg: chemical -> gene
    gemm(x_chem, W_src_cg, b_src_cg, proj_src, Nc, 1.0f);
    gemm(x_gene, W_dst_cg, b_dst_cg, proj_dst, Ng, 1.0f);
    edge_aggr<1><<<(E + 3) / 4, 256, 0, stream>>>(proj_src, proj_dst, ei_cg, E,
                                                  gtab_cg, ea_cg, aggr_gene, 0, E);

    // 5) cp: chemical -> go_term
    gemm(x_chem, W_src_cp, b_src_cp, proj_src, Nc, 1.0f);
    gemm(x_go,   W_dst_cp, b_dst_cp, proj_dst, Ngo, 1.0f);
    edge_aggr<2><<<(E + 3) / 4, 256, 0, stream>>>(proj_src, proj_dst, ei_cp, E,
                                                  gtab_cp, ea_cp, aggr_go, 0, E);

    // 6) ce: chemical -> pathway (continuous gate, chunked)
    gemm(x_chem, W_src_ce, b_src_ce, proj_src, Nc, 1.0f);
    gemm(x_pw,   W_dst_ce, b_dst_ce, proj_dst, Np, 1.0f);
    for (int base = 0; base < E; base += CHUNK) {
        int cnt = E - base; if (cnt > CHUNK) cnt = CHUNK;
        dim3 grid((cnt + 63) / 64, 4);
        gate_ce_gemm<<<grid, 256, 0, stream>>>(ea_ce, W_gate1_ce, b_gate1_ce,
                                               W_gate2_ce, b_gate2_ce, gate_ce, base, cnt);
        edge_aggr<3><<<(cnt + 3) / 4, 256, 0, stream>>>(proj_src, proj_dst, ei_ce, E,
                                                        gate_ce, nullptr, aggr_pw, base, cnt);
    }

    // 7) gg: gene -> gene (no gate), accumulates into aggr_gene
    gemm(x_gene, W_src_gg, b_src_gg, proj_src, Ng, 1.0f);
    gemm(x_gene, W_dst_gg, b_dst_gg, proj_dst, Ng, 1.0f);
    edge_aggr<0><<<(E + 3) / 4, 256, 0, stream>>>(proj_src, proj_dst, ei_gg, E,
                                                  nullptr, nullptr, aggr_gene, 0, E);

    // 8) output heads. Attention mean == 0.25 folded into alpha;
    //    gene branch additionally has the 0.5 from 0.5*(aggr_cg+aggr_gg).
    gemm(aggr_gene, W_out_gene, b_out_gene, out_gene, Ng, 0.125f);
    gemm(aggr_go,   W_out_go,   b_out_go,   out_go,   Ngo, 0.25f);
    gemm(aggr_pw,   W_out_pw,   b_out_pw,   out_pw,   Np,  0.25f);
}

// Round 2
// 1699.042 us; speedup vs baseline: 2.3537x; 2.3537x over previous
//
#include <hip/hip_runtime.h>
#include <math.h>

#define CD 256

__device__ __forceinline__ float sigmoidf_(float x) { return 1.0f / (1.0f + expf(-x)); }
__device__ __forceinline__ float geluf_(float x) { return 0.5f * x * (1.0f + erff(x * 0.70710678118654752f)); }

// ---------------------------------------------------------------------------
// Generic Y[N,256] = alpha*(X[N,256] @ W[256,256]) + bias, fp32 tiled.
// Optionally X2 != nullptr: A-operand is (X + X2) elementwise (used to fuse
// aggr_cg + aggr_gg without an extra pass).
// ---------------------------------------------------------------------------
__global__ __launch_bounds__(256) void gemm_bias(
    const float* __restrict__ X, const float* __restrict__ W,
    const float* __restrict__ bias, float* __restrict__ Y,
    int N, float alpha)
{
    __shared__ float Xs[64][68];  // [k][row]
    __shared__ float Ws[64][68];  // [k][col]
    const int tid  = threadIdx.x;
    const int row0 = blockIdx.x * 64;
    const int col0 = blockIdx.y * 64;
    const int tx = tid & 15;
    const int ty = tid >> 4;
    float acc[4][4] = {};

    for (int k0 = 0; k0 < CD; k0 += 64) {
#pragma unroll
        for (int m = 0; m < 4; ++m) {
            int flat = tid + m * 256;
            int r  = flat >> 4;
            int kq = flat & 15;
            int gr = row0 + r; gr = (gr < N) ? gr : (N - 1);
            float4 v = *(const float4*)(X + (size_t)gr * CD + k0 + kq * 4);
            Xs[kq * 4 + 0][r] = v.x;
            Xs[kq * 4 + 1][r] = v.y;
            Xs[kq * 4 + 2][r] = v.z;
            Xs[kq * 4 + 3][r] = v.w;
        }
#pragma unroll
        for (int m = 0; m < 4; ++m) {
            int flat = tid + m * 256;
            int k  = flat >> 4;
            int cq = flat & 15;
            float4 v = *(const float4*)(W + (size_t)(k0 + k) * CD + col0 + cq * 4);
            *(float4*)&Ws[k][cq * 4] = v;
        }
        __syncthreads();
#pragma unroll
        for (int k = 0; k < 64; ++k) {
            float4 a = *(const float4*)&Xs[k][ty * 4];
            float4 b = *(const float4*)&Ws[k][tx * 4];
            acc[0][0] += a.x * b.x; acc[0][1] += a.x * b.y; acc[0][2] += a.x * b.z; acc[0][3] += a.x * b.w;
            acc[1][0] += a.y * b.x; acc[1][1] += a.y * b.y; acc[1][2] += a.y * b.z; acc[1][3] += a.y * b.w;
            acc[2][0] += a.z * b.x; acc[2][1] += a.z * b.y; acc[2][2] += a.z * b.z; acc[2][3] += a.z * b.w;
            acc[3][0] += a.w * b.x; acc[3][1] += a.w * b.y; acc[3][2] += a.w * b.z; acc[3][3] += a.w * b.w;
        }
        __syncthreads();
    }
#pragma unroll
    for (int i = 0; i < 4; ++i) {
        int row = row0 + ty * 4 + i;
        if (row < N) {
            int col = col0 + tx * 4;
            float4 bb = *(const float4*)(bias + col);
            float4 o;
            o.x = alpha * acc[i][0] + bb.x;
            o.y = alpha * acc[i][1] + bb.y;
            o.z = alpha * acc[i][2] + bb.z;
            o.w = alpha * acc[i][3] + bb.w;
            *(float4*)(Y + (size_t)row * CD + col) = o;
        }
    }
}

// ---------------------------------------------------------------------------
// ce gate in CSR order: G[r,:] = sigmoid( gelu(ea[col[jb+r],:3]@W1+b1) @ W2 + b2 )
// ---------------------------------------------------------------------------
__global__ __launch_bounds__(256) void gate_ce_gemm(
    const float* __restrict__ EA, const int* __restrict__ col,
    const float* __restrict__ W1, const float* __restrict__ b1,
    const float* __restrict__ W2, const float* __restrict__ b2,
    float* __restrict__ G, int jb, int count)
{
    __shared__ float Hs[64][68];
    __shared__ float Ws[64][68];
    const int tid  = threadIdx.x;
    const int row0 = blockIdx.x * 64;
    const int col0 = blockIdx.y * 64;
    const int tx = tid & 15;
    const int ty = tid >> 4;
    float acc[4][4] = {};

    for (int k0 = 0; k0 < CD; k0 += 64) {
#pragma unroll
        for (int m = 0; m < 4; ++m) {
            int flat = tid + m * 256;
            int r  = flat >> 4;
            int kq = flat & 15;
            int rr = row0 + r; rr = (rr < count) ? rr : (count - 1);
            int e  = col[jb + rr];
            size_t eo = (size_t)e * 3;
            float a0 = EA[eo], a1 = EA[eo + 1], a2 = EA[eo + 2];
            int kk = k0 + kq * 4;
            float4 w0 = *(const float4*)(W1 + kk);
            float4 w1 = *(const float4*)(W1 + CD + kk);
            float4 w2 = *(const float4*)(W1 + 2 * CD + kk);
            float4 bb = *(const float4*)(b1 + kk);
            Hs[kq * 4 + 0][r] = geluf_(a0 * w0.x + a1 * w1.x + a2 * w2.x + bb.x);
            Hs[kq * 4 + 1][r] = geluf_(a0 * w0.y + a1 * w1.y + a2 * w2.y + bb.y);
            Hs[kq * 4 + 2][r] = geluf_(a0 * w0.z + a1 * w1.z + a2 * w2.z + bb.z);
            Hs[kq * 4 + 3][r] = geluf_(a0 * w0.w + a1 * w1.w + a2 * w2.w + bb.w);
        }
#pragma unroll
        for (int m = 0; m < 4; ++m) {
            int flat = tid + m * 256;
            int k  = flat >> 4;
            int cq = flat & 15;
            float4 v = *(const float4*)(W2 + (size_t)(k0 + k) * CD + col0 + cq * 4);
            *(float4*)&Ws[k][cq * 4] = v;
        }
        __syncthreads();
#pragma unroll
        for (int k = 0; k < 64; ++k) {
            float4 a = *(const float4*)&Hs[k][ty * 4];
            float4 b = *(const float4*)&Ws[k][tx * 4];
            acc[0][0] += a.x * b.x; acc[0][1] += a.x * b.y; acc[0][2] += a.x * b.z; acc[0][3] += a.x * b.w;
            acc[1][0] += a.y * b.x; acc[1][1] += a.y * b.y; acc[1][2] += a.y * b.z; acc[1][3] += a.y * b.w;
            acc[2][0] += a.z * b.x; acc[2][1] += a.z * b.y; acc[2][2] += a.z * b.z; acc[2][3] += a.z * b.w;
            acc[3][0] += a.w * b.x; acc[3][1] += a.w * b.y; acc[3][2] += a.w * b.z; acc[3][3] += a.w * b.w;
        }
        __syncthreads();
    }
#pragma unroll
    for (int i = 0; i < 4; ++i) {
        int row = row0 + ty * 4 + i;
        if (row < count) {
            int c0 = col0 + tx * 4;
            float4 bb = *(const float4*)(b2 + c0);
            float4 o;
            o.x = sigmoidf_(acc[i][0] + bb.x);
            o.y = sigmoidf_(acc[i][1] + bb.y);
            o.z = sigmoidf_(acc[i][2] + bb.z);
            o.w = sigmoidf_(acc[i][3] + bb.w);
            *(float4*)(G + (size_t)row * CD + c0) = o;
        }
    }
}

// ---------------------------------------------------------------------------
// Gate lookup tables (cg: 50 combos, cp: 3 phenos)
// ---------------------------------------------------------------------------
__global__ void gate_cg_table_k(const float* __restrict__ embA, const float* __restrict__ embB,
                                const float* __restrict__ Wg, const float* __restrict__ bg,
                                float* __restrict__ tab)
{
    int combo = blockIdx.x;
    int a = combo / 5, b = combo % 5;
    int j = threadIdx.x;
    float s = bg[j];
    for (int k = 0; k < 32; ++k) s += embA[a * 32 + k] * Wg[k * CD + j];
    for (int k = 0; k < 32; ++k) s += embB[b * 32 + k] * Wg[(32 + k) * CD + j];
    tab[(size_t)combo * CD + j] = sigmoidf_(s);
}

__global__ void gate_cp_table_k(const float* __restrict__ embP, const float* __restrict__ Wg,
                                const float* __restrict__ bg, float* __restrict__ tab)
{
    int p = blockIdx.x;
    int j = threadIdx.x;
    float s = bg[j];
    for (int k = 0; k < 32; ++k) s += embP[p * 32 + k] * Wg[k * CD + j];
    tab[(size_t)p * CD + j] = sigmoidf_(s);
}

// ---------------------------------------------------------------------------
// CSR construction: histogram -> single-block exclusive scan -> scatter
// ---------------------------------------------------------------------------
__global__ void hist_k(const int* __restrict__ ei, int E, int* __restrict__ deg)
{
    int i = blockIdx.x * 256 + threadIdx.x;
    if (i < E) atomicAdd(&deg[ei[E + i]], 1);
}

__global__ __launch_bounds__(1024) void exscan_k(const int* __restrict__ deg,
                                                 int* __restrict__ rowptr, int n)
{
    __shared__ int psum[1024];
    int tid = threadIdx.x;
    int per = (n + 1023) / 1024;
    int lo = tid * per;
    int hi = lo + per; if (hi > n) hi = n; if (lo > n) lo = n;
    int s = 0;
    for (int i = lo; i < hi; ++i) s += deg[i];
    psum[tid] = s;
    __syncthreads();
    for (int off = 1; off < 1024; off <<= 1) {
        int t = (tid >= off) ? psum[tid - off] : 0;
        __syncthreads();
        psum[tid] += t;
        __syncthreads();
    }
    int run = psum[tid] - s;   // exclusive prefix of this thread's chunk
    for (int i = lo; i < hi; ++i) { rowptr[i] = run; run += deg[i]; }
    if (tid == 1023) rowptr[n] = psum[1023];
}

__global__ void scatter_k(const int* __restrict__ ei, int E,
                          const int* __restrict__ rowptr, int* __restrict__ cursor,
                          int* __restrict__ col)
{
    int i = blockIdx.x * 256 + threadIdx.x;
    if (i < E) {
        int d = ei[E + i];
        int pos = rowptr[d] + atomicAdd(&cursor[d], 1);
        col[pos] = i;
    }
}

// ---------------------------------------------------------------------------
// Destination-major aggregation: one wave per dest row, register accumulate,
// single store (no float atomics).
//   aggr[d] = sum_e g[e] (x) Psrc[si_e]  +  (sum_e g[e]) (x) Pdst[d]  [+ aggr[d]]
// MODE: 0 = no gate (gg), 1 = cg table (a*5+b), 2 = cp table
// ADDIN: 1 -> read-modify-write existing aggr row (row owned by this wave)
// ---------------------------------------------------------------------------
template <int MODE, int ADDIN>
__global__ __launch_bounds__(256) void dest_aggr(
    const float* __restrict__ Psrc, const float* __restrict__ Pdst,
    const int* __restrict__ ei, int E,
    const int* __restrict__ rowptr, const int* __restrict__ col,
    const float* __restrict__ gate, const int* __restrict__ eai,
    float* __restrict__ aggr, int n_dst)
{
    int d = blockIdx.x * 4 + (threadIdx.x >> 6);
    if (d >= n_dst) return;
    int lane = threadIdx.x & 63;
    int js = rowptr[d], je = rowptr[d + 1];
    float4 accS = {0.f, 0.f, 0.f, 0.f};
    float4 accG = {0.f, 0.f, 0.f, 0.f};
    for (int j = js; j < je; ++j) {
        int e  = col[j];
        int si = ei[e];
        float4 s = *(const float4*)(Psrc + (size_t)si * CD + lane * 4);
        if (MODE == 0) {
            accS.x += s.x; accS.y += s.y; accS.z += s.z; accS.w += s.w;
        } else {
            float4 g;
            if (MODE == 1) {
                int a = eai[2 * e], b = eai[2 * e + 1];
                g = *(const float4*)(gate + (size_t)(a * 5 + b) * CD + lane * 4);
            } else {
                int p = eai[e];
                g = *(const float4*)(gate + (size_t)p * CD + lane * 4);
            }
            accS.x += g.x * s.x; accS.y += g.y * s.y; accS.z += g.z * s.z; accS.w += g.w * s.w;
            accG.x += g.x; accG.y += g.y; accG.z += g.z; accG.w += g.w;
        }
    }
    float4 dv = *(const float4*)(Pdst + (size_t)d * CD + lane * 4);
    float cnt = (float)(je - js);
    float4 r;
    if (MODE == 0) {
        r.x = accS.x + cnt * dv.x; r.y = accS.y + cnt * dv.y;
        r.z = accS.z + cnt * dv.z; r.w = accS.w + cnt * dv.w;
    } else {
        r.x = accS.x + accG.x * dv.x; r.y = accS.y + accG.y * dv.y;
        r.z = accS.z + accG.z * dv.z; r.w = accS.w + accG.w * dv.w;
    }
    float* ap = aggr + (size_t)d * CD + lane * 4;
    if (ADDIN) {
        float4 old = *(const float4*)ap;
        r.x += old.x; r.y += old.y; r.z += old.z; r.w += old.w;
    }
    *(float4*)ap = r;
}

// ce: per-edge gate buffer in CSR order, j-window [jb, jend); few boundary
// dests per chunk -> atomicAdd is cheap (aggr_pw zeroed beforehand).
__global__ __launch_bounds__(256) void ce_aggr_chunk(
    const float* __restrict__ Psrc, const float* __restrict__ Pdst,
    const int* __restrict__ ei, int E,
    const int* __restrict__ rowptr, const int* __restrict__ col,
    const float* __restrict__ G,
    float* __restrict__ aggr, int n_dst, int jb, int jend)
{
    int d = blockIdx.x * 4 + (threadIdx.x >> 6);
    if (d >= n_dst) return;
    int lane = threadIdx.x & 63;
    int lo = rowptr[d];     if (lo < jb)  lo = jb;
    int hi = rowptr[d + 1]; if (hi > jend) hi = jend;
    if (lo >= hi) return;
    float4 accS = {0.f, 0.f, 0.f, 0.f};
    float4 accG = {0.f, 0.f, 0.f, 0.f};
    for (int j = lo; j < hi; ++j) {
        int e  = col[j];
        int si = ei[e];
        float4 s = *(const float4*)(Psrc + (size_t)si * CD + lane * 4);
        float4 g = *(const float4*)(G + (size_t)(j - jb) * CD + lane * 4);
        accS.x += g.x * s.x; accS.y += g.y * s.y; accS.z += g.z * s.z; accS.w += g.w * s.w;
        accG.x += g.x; accG.y += g.y; accG.z += g.z; accG.w += g.w;
    }
    float4 dv = *(const float4*)(Pdst + (size_t)d * CD + lane * 4);
    float* ap = aggr + (size_t)d * CD + lane * 4;
    atomicAdd(ap + 0, accS.x + accG.x * dv.x);
    atomicAdd(ap + 1, accS.y + accG.y * dv.y);
    atomicAdd(ap + 2, accS.z + accG.z * dv.z);
    atomicAdd(ap + 3, accS.w + accG.w * dv.w);
}

// ---------------------------------------------------------------------------
extern "C" void kernel_launch(void* const* d_in, const int* in_sizes, int n_in,
                              void* d_out, int out_size, void* d_ws, size_t ws_size,
                              hipStream_t stream)
{
    const float* x_chem = (const float*)d_in[0];
    const float* x_gene = (const float*)d_in[1];
    const float* x_go   = (const float*)d_in[2];
    const float* x_pw   = (const float*)d_in[3];
    const int*   ei_cg  = (const int*)d_in[4];
    const int*   ei_cp  = (const int*)d_in[5];
    const int*   ei_ce  = (const int*)d_in[6];
    const int*   ei_gg  = (const int*)d_in[7];
    const int*   ea_cg  = (const int*)d_in[8];
    const int*   ea_cp  = (const int*)d_in[9];
    const float* ea_ce  = (const float*)d_in[10];

    const float* W_src_cg = (const float*)d_in[11];
    const float* b_src_cg = (const float*)d_in[12];
    const float* W_dst_cg = (const float*)d_in[13];
    const float* b_dst_cg = (const float*)d_in[14];
    const float* W_src_cp = (const float*)d_in[16];
    const float* b_src_cp = (const float*)d_in[17];
    const float* W_dst_cp = (const float*)d_in[18];
    const float* b_dst_cp = (const float*)d_in[19];
    const float* W_src_ce = (const float*)d_in[21];
    const float* b_src_ce = (const float*)d_in[22];
    const float* W_dst_ce = (const float*)d_in[23];
    const float* b_dst_ce = (const float*)d_in[24];
    const float* W_src_gg = (const float*)d_in[26];
    const float* b_src_gg = (const float*)d_in[27];
    const float* W_dst_gg = (const float*)d_in[28];
    const float* b_dst_gg = (const float*)d_in[29];

    const float* emb_at   = (const float*)d_in[31];
    const float* emb_as   = (const float*)d_in[32];
    const float* W_gate_cg = (const float*)d_in[33];
    const float* b_gate_cg = (const float*)d_in[34];
    const float* emb_ph   = (const float*)d_in[35];
    const float* W_gate_cp = (const float*)d_in[36];
    const float* b_gate_cp = (const float*)d_in[37];
    const float* W_gate1_ce = (const float*)d_in[38];
    const float* b_gate1_ce = (const float*)d_in[39];
    const float* W_gate2_ce = (const float*)d_in[40];
    const float* b_gate2_ce = (const float*)d_in[41];
    const float* W_out_gene = (const float*)d_in[42];
    const float* b_out_gene = (const float*)d_in[43];
    const float* W_out_go   = (const float*)d_in[44];
    const float* b_out_go   = (const float*)d_in[45];
    const float* W_out_pw   = (const float*)d_in[46];
    const float* b_out_pw   = (const float*)d_in[47];

    const int Nc  = in_sizes[0] / CD;
    const int Ng  = in_sizes[1] / CD;
    const int Ngo = in_sizes[2] / CD;
    const int Np  = in_sizes[3] / CD;
    const int E   = in_sizes[4] / 2;

    // ---- workspace layout ----
    float* ws = (float*)d_ws;
    size_t off = 0;
    float* aggr_gene = ws + off; off += (size_t)Ng  * CD;
    float* aggr_go   = ws + off; off += (size_t)Ngo * CD;
    float* aggr_pw   = ws + off; off += (size_t)Np  * CD;
    int maxSrc = (Nc > Ng) ? Nc : Ng;
    int maxDst = Ng; if (Ngo > maxDst) maxDst = Ngo; if (Np > maxDst) maxDst = Np;
    float* proj_src = ws + off; off += (size_t)maxSrc * CD;
    float* proj_dst = ws + off; off += (size_t)maxDst * CD;
    float* gtab_cg  = ws + off; off += 50 * CD;
    float* gtab_cp  = ws + off; off += 3 * CD;
    // CSR int arrays (reused serially across edge types)
    int* deg    = (int*)(ws + off); off += (size_t)(maxDst + 1);
    int* cursor = (int*)(ws + off); off += (size_t)(maxDst + 1);
    int* rowptr = (int*)(ws + off); off += (size_t)(maxDst + 2);
    int* colv   = (int*)(ws + off); off += (size_t)E;
    // remaining -> ce gate chunk buffer (CSR-ordered)
    float* gate_ce  = ws + off;
    size_t remaining = ws_size / 4 - off;
    long long CHUNKll = (long long)(remaining / CD);
    int CHUNK = (CHUNKll > E) ? E : (int)CHUNKll;
    if (CHUNK < 1) CHUNK = 1;

    float* out_gene = (float*)d_out + (size_t)Nc * CD;
    float* out_go   = out_gene + (size_t)Ng * CD;
    float* out_pw   = out_go + (size_t)Ngo * CD;

    const int EB = (E + 255) / 256;

    auto gemm = [&](const float* X, const float* W, const float* b, float* Y, int N, float alpha) {
        dim3 grid((N + 63) / 64, 4);
        gemm_bias<<<grid, 256, 0, stream>>>(X, W, b, Y, N, alpha);
    };
    auto build_csr = [&](const int* ei, int n_dst) {
        hipMemsetAsync(deg, 0, (size_t)(n_dst + 1) * sizeof(int), stream);
        hipMemsetAsync(cursor, 0, (size_t)(n_dst + 1) * sizeof(int), stream);
        hist_k<<<EB, 256, 0, stream>>>(ei, E, deg);
        exscan_k<<<1, 1024, 0, stream>>>(deg, rowptr, n_dst);
        scatter_k<<<EB, 256, 0, stream>>>(ei, E, rowptr, cursor, colv);
    };

    // 1) passthrough copy: x_chemical -> out[0]
    hipMemcpyAsync(d_out, x_chem, (size_t)Nc * CD * sizeof(float),
                   hipMemcpyDeviceToDevice, stream);

    // 2) gate tables
    gate_cg_table_k<<<50, 256, 0, stream>>>(emb_at, emb_as, W_gate_cg, b_gate_cg, gtab_cg);
    gate_cp_table_k<<<3, 256, 0, stream>>>(emb_ph, W_gate_cp, b_gate_cp, gtab_cp);

    // 3) cg: chemical -> gene (store into aggr_gene)
    gemm(x_chem, W_src_cg, b_src_cg, proj_src, Nc, 1.0f);
    gemm(x_gene, W_dst_cg, b_dst_cg, proj_dst, Ng, 1.0f);
    build_csr(ei_cg, Ng);
    dest_aggr<1, 0><<<(Ng + 3) / 4, 256, 0, stream>>>(proj_src, proj_dst, ei_cg, E,
                                                      rowptr, colv, gtab_cg, ea_cg,
                                                      aggr_gene, Ng);

    // 4) cp: chemical -> go_term
    gemm(x_chem, W_src_cp, b_src_cp, proj_src, Nc, 1.0f);
    gemm(x_go,   W_dst_cp, b_dst_cp, proj_dst, Ngo, 1.0f);
    build_csr(ei_cp, Ngo);
    dest_aggr<2, 0><<<(Ngo + 3) / 4, 256, 0, stream>>>(proj_src, proj_dst, ei_cp, E,
                                                       rowptr, colv, gtab_cp, ea_cp,
                                                       aggr_go, Ngo);

    // 5) ce: chemical -> pathway (continuous gate, CSR-ordered chunks)
    gemm(x_chem, W_src_ce, b_src_ce, proj_src, Nc, 1.0f);
    gemm(x_pw,   W_dst_ce, b_dst_ce, proj_dst, Np, 1.0f);
    build_csr(ei_ce, Np);
    hipMemsetAsync(aggr_pw, 0, (size_t)Np * CD * sizeof(float), stream);
    for (int jb = 0; jb < E; jb += CHUNK) {
        int cnt = E - jb; if (cnt > CHUNK) cnt = CHUNK;
        dim3 grid((cnt + 63) / 64, 4);
        gate_ce_gemm<<<grid, 256, 0, stream>>>(ea_ce, colv, W_gate1_ce, b_gate1_ce,
                                               W_gate2_ce, b_gate2_ce, gate_ce, jb, cnt);
        ce_aggr_chunk<<<(Np + 3) / 4, 256, 0, stream>>>(proj_src, proj_dst, ei_ce, E,
                                                        rowptr, colv, gate_ce,
                                                        aggr_pw, Np, jb, jb + cnt);
    }

    // 6) gg: gene -> gene (no gate), read-add-store into aggr_gene
    gemm(x_gene, W_src_gg, b_src_gg, proj_src, Ng, 1.0f);
    gemm(x_gene, W_dst_gg, b_dst_gg, proj_dst, Ng, 1.0f);
    build_csr(ei_gg, Ng);
    dest_aggr<0, 1><<<(Ng + 3) / 4, 256, 0, stream>>>(proj_src, proj_dst, ei_gg, E,
                                                      rowptr, colv, nullptr, nullptr,
                                                      aggr_gene, Ng);

    // 7) output heads (attention mean == 0.25 folded into alpha; gene branch
    //    additionally has the 0.5 from 0.5*(aggr_cg+aggr_gg))
    gemm(aggr_gene, W_out_gene, b_out_gene, out_gene, Ng, 0.125f);
    gemm(aggr_go,   W_out_go,   b_out_go,   out_go,   Ngo, 0.25f);
    gemm(aggr_pw,   W_out_pw,   b_out_pw,   out_pw,   Np,  0.25f);
}

// Round 5
// 1257.622 us; speedup vs baseline: 3.1798x; 1.3510x over previous
//
#include <hip/hip_runtime.h>
#include <math.h>

#define CD 256

typedef unsigned short u16;
typedef __attribute__((ext_vector_type(8))) short short8;
typedef __attribute__((ext_vector_type(4))) float f32x4;

__device__ __forceinline__ float sigmoidf_(float x) { return 1.0f / (1.0f + expf(-x)); }
__device__ __forceinline__ float geluf_(float x) { return 0.5f * x * (1.0f + erff(x * 0.70710678118654752f)); }

__device__ __forceinline__ u16 f2bf(float x) {
    union { float f; unsigned u; } v; v.f = x;
    unsigned r = v.u + 0x7FFF + ((v.u >> 16) & 1);   // RNE
    return (u16)(r >> 16);
}
__device__ __forceinline__ float bf2f(u16 h) {
    union { unsigned u; float f; } v; v.u = ((unsigned)h) << 16;
    return v.f;
}
__device__ __forceinline__ float4 ld_bf4(const u16* p) {
    ushort4 u = *(const ushort4*)p;
    float4 f; f.x = bf2f(u.x); f.y = bf2f(u.y); f.z = bf2f(u.z); f.w = bf2f(u.w);
    return f;
}

// ---------------------------------------------------------------------------
// bf16 MFMA GEMM: Y[N,256] = alpha*(A[N,256] @ W) + bias
// A fp32 row-major (converted to bf16 during LDS staging);
// Wt bf16 with Wt[n][k] = W[k][n].
// Block: 256 thr, 64 rows x 256 cols; wave w owns cols [64w,64w+64).
// ---------------------------------------------------------------------------
template <int OUT_BF16>
__global__ __launch_bounds__(256) void gemm_mfma(
    const float* __restrict__ A, const u16* __restrict__ Wt,
    const float* __restrict__ bias, float* __restrict__ Yf, u16* __restrict__ Yb,
    int N, float alpha)
{
    __shared__ __align__(16) u16 As[64][72];
    __shared__ __align__(16) u16 Ws[256][72];
    const int tid = threadIdx.x;
    const int row0 = blockIdx.x * 64;
    const int wave = tid >> 6, lane = tid & 63;
    const int quad = lane >> 4, l16 = lane & 15;
    f32x4 acc[4][4] = {};   // [mi][ni]

    const int r = tid >> 2, seg = tid & 3;
    int gr = row0 + r; if (gr >= N) gr = N - 1;

    for (int k0 = 0; k0 < CD; k0 += 64) {
        const float* ap = A + (size_t)gr * CD + k0 + seg * 16;
#pragma unroll
        for (int i = 0; i < 16; i += 4) {
            float4 v = *(const float4*)(ap + i);
            As[r][seg * 16 + i + 0] = f2bf(v.x);
            As[r][seg * 16 + i + 1] = f2bf(v.y);
            As[r][seg * 16 + i + 2] = f2bf(v.z);
            As[r][seg * 16 + i + 3] = f2bf(v.w);
        }
        const u16* wp = Wt + (size_t)tid * CD + k0;
#pragma unroll
        for (int q = 0; q < 8; ++q)
            *(short8*)&Ws[tid][q * 8] = *(const short8*)(wp + q * 8);
        __syncthreads();
#pragma unroll
        for (int ks = 0; ks < 64; ks += 32) {
            short8 af[4], bf[4];
#pragma unroll
            for (int mi = 0; mi < 4; ++mi)
                af[mi] = *(const short8*)&As[mi * 16 + l16][ks + quad * 8];
#pragma unroll
            for (int ni = 0; ni < 4; ++ni)
                bf[ni] = *(const short8*)&Ws[wave * 64 + ni * 16 + l16][ks + quad * 8];
#pragma unroll
            for (int mi = 0; mi < 4; ++mi)
#pragma unroll
                for (int ni = 0; ni < 4; ++ni)
                    acc[mi][ni] = __builtin_amdgcn_mfma_f32_16x16x32_bf16(
                        af[mi], bf[ni], acc[mi][ni], 0, 0, 0);
        }
        __syncthreads();
    }
#pragma unroll
    for (int mi = 0; mi < 4; ++mi)
#pragma unroll
        for (int rr = 0; rr < 4; ++rr) {
            int m = mi * 16 + quad * 4 + rr;
            int grow = row0 + m;
            if (grow < N) {
#pragma unroll
                for (int ni = 0; ni < 4; ++ni) {
                    int n = wave * 64 + ni * 16 + l16;
                    float v = alpha * acc[mi][ni][rr] + bias[n];
                    if (OUT_BF16) Yb[(size_t)grow * CD + n] = f2bf(v);
                    else          Yf[(size_t)grow * CD + n] = v;
                }
            }
        }
}

// ---------------------------------------------------------------------------
// ce gate, MFMA: G[r,:] = sigmoid( gelu(ea[col[jb+r],:3]@W1+b1) @ W2 + b2 ), bf16 out
// ---------------------------------------------------------------------------
__global__ __launch_bounds__(256) void gate_ce_mfma(
    const float* __restrict__ EA, const int* __restrict__ col,
    const float* __restrict__ W1, const float* __restrict__ b1,
    const u16* __restrict__ W2t, const float* __restrict__ b2,
    u16* __restrict__ G, int jb, int count)
{
    __shared__ __align__(16) u16 As[64][72];
    __shared__ __align__(16) u16 Ws[256][72];
    const int tid = threadIdx.x;
    const int row0 = blockIdx.x * 64;
    const int wave = tid >> 6, lane = tid & 63;
    const int quad = lane >> 4, l16 = lane & 15;
    f32x4 acc[4][4] = {};

    const int r = tid >> 2, seg = tid & 3;
    int rr0 = row0 + r; if (rr0 >= count) rr0 = count - 1;
    const int e = col[jb + rr0];
    const float a0 = EA[(size_t)e * 3], a1 = EA[(size_t)e * 3 + 1], a2 = EA[(size_t)e * 3 + 2];

    for (int k0 = 0; k0 < CD; k0 += 64) {
        int kk = k0 + seg * 16;
#pragma unroll
        for (int i = 0; i < 16; i += 4) {
            float4 w0 = *(const float4*)(W1 + kk + i);
            float4 w1 = *(const float4*)(W1 + CD + kk + i);
            float4 w2 = *(const float4*)(W1 + 2 * CD + kk + i);
            float4 bb = *(const float4*)(b1 + kk + i);
            As[r][seg * 16 + i + 0] = f2bf(geluf_(a0 * w0.x + a1 * w1.x + a2 * w2.x + bb.x));
            As[r][seg * 16 + i + 1] = f2bf(geluf_(a0 * w0.y + a1 * w1.y + a2 * w2.y + bb.y));
            As[r][seg * 16 + i + 2] = f2bf(geluf_(a0 * w0.z + a1 * w1.z + a2 * w2.z + bb.z));
            As[r][seg * 16 + i + 3] = f2bf(geluf_(a0 * w0.w + a1 * w1.w + a2 * w2.w + bb.w));
        }
        const u16* wp = W2t + (size_t)tid * CD + k0;
#pragma unroll
        for (int q = 0; q < 8; ++q)
            *(short8*)&Ws[tid][q * 8] = *(const short8*)(wp + q * 8);
        __syncthreads();
#pragma unroll
        for (int ks = 0; ks < 64; ks += 32) {
            short8 af[4], bf[4];
#pragma unroll
            for (int mi = 0; mi < 4; ++mi)
                af[mi] = *(const short8*)&As[mi * 16 + l16][ks + quad * 8];
#pragma unroll
            for (int ni = 0; ni < 4; ++ni)
                bf[ni] = *(const short8*)&Ws[wave * 64 + ni * 16 + l16][ks + quad * 8];
#pragma unroll
            for (int mi = 0; mi < 4; ++mi)
#pragma unroll
                for (int ni = 0; ni < 4; ++ni)
                    acc[mi][ni] = __builtin_amdgcn_mfma_f32_16x16x32_bf16(
                        af[mi], bf[ni], acc[mi][ni], 0, 0, 0);
        }
        __syncthreads();
    }
#pragma unroll
    for (int mi = 0; mi < 4; ++mi)
#pragma unroll
        for (int rr = 0; rr < 4; ++rr) {
            int m = mi * 16 + quad * 4 + rr;
            int grow = row0 + m;
            if (grow < count) {
#pragma unroll
                for (int ni = 0; ni < 4; ++ni) {
                    int n = wave * 64 + ni * 16 + l16;
                    G[(size_t)grow * CD + n] = f2bf(sigmoidf_(acc[mi][ni][rr] + b2[n]));
                }
            }
        }
}

// ---------------------------------------------------------------------------
// Weight transpose+convert: Wt[n][k] = bf16(W[k][n]) for 12 matrices at once.
// ---------------------------------------------------------------------------
struct WtArgs { const float* src[12]; u16* dst[12]; };

__global__ __launch_bounds__(256) void wtrans_k(WtArgs a)
{
    __shared__ float t[64][65];
    const int mat = blockIdx.y;
    const int tile = blockIdx.x;            // 16 tiles of 64x64
    const int tr = tile >> 2, tc = tile & 3;
    const int r = threadIdx.x >> 2, seg = threadIdx.x & 3;
    const float* S = a.src[mat];
    u16* D = a.dst[mat];
#pragma unroll
    for (int i = 0; i < 16; i += 4) {
        float4 v = *(const float4*)(S + (size_t)(tr * 64 + r) * CD + tc * 64 + seg * 16 + i);
        t[r][seg * 16 + i + 0] = v.x;
        t[r][seg * 16 + i + 1] = v.y;
        t[r][seg * 16 + i + 2] = v.z;
        t[r][seg * 16 + i + 3] = v.w;
    }
    __syncthreads();
#pragma unroll
    for (int i = 0; i < 16; ++i)
        D[(size_t)(tc * 64 + r) * CD + tr * 64 + seg * 16 + i] = f2bf(t[seg * 16 + i][r]);
}

// ---------------------------------------------------------------------------
// Gate lookup tables (cg: 50 combos, cp: 3 phenos), fp32
// ---------------------------------------------------------------------------
__global__ void gate_cg_table_k(const float* __restrict__ embA, const float* __restrict__ embB,
                                const float* __restrict__ Wg, const float* __restrict__ bg,
                                float* __restrict__ tab)
{
    int combo = blockIdx.x;
    int a = combo / 5, b = combo % 5;
    int j = threadIdx.x;
    float s = bg[j];
    for (int k = 0; k < 32; ++k) s += embA[a * 32 + k] * Wg[k * CD + j];
    for (int k = 0; k < 32; ++k) s += embB[b * 32 + k] * Wg[(32 + k) * CD + j];
    tab[(size_t)combo * CD + j] = sigmoidf_(s);
}

__global__ void gate_cp_table_k(const float* __restrict__ embP, const float* __restrict__ Wg,
                                const float* __restrict__ bg, float* __restrict__ tab)
{
    int p = blockIdx.x;
    int j = threadIdx.x;
    float s = bg[j];
    for (int k = 0; k < 32; ++k) s += embP[p * 32 + k] * Wg[k * CD + j];
    tab[(size_t)p * CD + j] = sigmoidf_(s);
}

// ---------------------------------------------------------------------------
// CSR construction
// ---------------------------------------------------------------------------
__global__ void hist_k(const int* __restrict__ ei, int E, int* __restrict__ deg)
{
    int i = blockIdx.x * 256 + threadIdx.x;
    if (i < E) atomicAdd(&deg[ei[E + i]], 1);
}

__global__ __launch_bounds__(1024) void exscan_k(const int* __restrict__ deg,
                                                 int* __restrict__ rowptr, int n)
{
    __shared__ int psum[1024];
    int tid = threadIdx.x;
    int per = (n + 1023) / 1024;
    int lo = tid * per;
    int hi = lo + per; if (hi > n) hi = n; if (lo > n) lo = n;
    int s = 0;
    for (int i = lo; i < hi; ++i) s += deg[i];
    psum[tid] = s;
    __syncthreads();
    for (int off = 1; off < 1024; off <<= 1) {
        int t = (tid >= off) ? psum[tid - off] : 0;
        __syncthreads();
        psum[tid] += t;
        __syncthreads();
    }
    int run = psum[tid] - s;
    for (int i = lo; i < hi; ++i) { rowptr[i] = run; run += deg[i]; }
    if (tid == 1023) rowptr[n] = psum[1023];
}

__global__ void scatter_k(const int* __restrict__ ei, int E,
                          const int* __restrict__ rowptr, int* __restrict__ cursor,
                          int* __restrict__ col)
{
    int i = blockIdx.x * 256 + threadIdx.x;
    if (i < E) {
        int d = ei[E + i];
        int pos = rowptr[d] + atomicAdd(&cursor[d], 1);
        col[pos] = i;
    }
}

// ---------------------------------------------------------------------------
// Destination-major aggregation (bf16 proj, fp32 gate tables, fp32 out)
// MODE: 0 = no gate (gg), 1 = cg table, 2 = cp table ; ADDIN: rmw aggr row
// ---------------------------------------------------------------------------
template <int MODE, int ADDIN>
__global__ __launch_bounds__(256) void dest_aggr(
    const u16* __restrict__ Psrc, const u16* __restrict__ Pdst,
    const int* __restrict__ ei, int E,
    const int* __restrict__ rowptr, const int* __restrict__ col,
    const float* __restrict__ gate, const int* __restrict__ eai,
    float* __restrict__ aggr, int n_dst)
{
    int d = blockIdx.x * 4 + (threadIdx.x >> 6);
    if (d >= n_dst) return;
    int lane = threadIdx.x & 63;
    int js = rowptr[d], je = rowptr[d + 1];
    float4 accS = {0.f, 0.f, 0.f, 0.f};
    float4 accG = {0.f, 0.f, 0.f, 0.f};
    for (int j = js; j < je; ++j) {
        int e  = col[j];
        int si = ei[e];
        float4 s = ld_bf4(Psrc + (size_t)si * CD + lane * 4);
        if (MODE == 0) {
            accS.x += s.x; accS.y += s.y; accS.z += s.z; accS.w += s.w;
        } else {
            float4 g;
            if (MODE == 1) {
                int a = eai[2 * e], b = eai[2 * e + 1];
                g = *(const float4*)(gate + (size_t)(a * 5 + b) * CD + lane * 4);
            } else {
                int p = eai[e];
                g = *(const float4*)(gate + (size_t)p * CD + lane * 4);
            }
            accS.x += g.x * s.x; accS.y += g.y * s.y; accS.z += g.z * s.z; accS.w += g.w * s.w;
            accG.x += g.x; accG.y += g.y; accG.z += g.z; accG.w += g.w;
        }
    }
    float4 dv = ld_bf4(Pdst + (size_t)d * CD + lane * 4);
    float cnt = (float)(je - js);
    float4 r;
    if (MODE == 0) {
        r.x = accS.x + cnt * dv.x; r.y = accS.y + cnt * dv.y;
        r.z = accS.z + cnt * dv.z; r.w = accS.w + cnt * dv.w;
    } else {
        r.x = accS.x + accG.x * dv.x; r.y = accS.y + accG.y * dv.y;
        r.z = accS.z + accG.z * dv.z; r.w = accS.w + accG.w * dv.w;
    }
    float* ap = aggr + (size_t)d * CD + lane * 4;
    if (ADDIN) {
        float4 old = *(const float4*)ap;
        r.x += old.x; r.y += old.y; r.z += old.z; r.w += old.w;
    }
    *(float4*)ap = r;
}

// ce: bf16 gate buffer in CSR order, j-window [jb, jend)
__global__ __launch_bounds__(256) void ce_aggr_chunk(
    const u16* __restrict__ Psrc, const u16* __restrict__ Pdst,
    const int* __restrict__ ei, int E,
    const int* __restrict__ rowptr, const int* __restrict__ col,
    const u16* __restrict__ G,
    float* __restrict__ aggr, int n_dst, int jb, int jend)
{
    int d = blockIdx.x * 4 + (threadIdx.x >> 6);
    if (d >= n_dst) return;
    int lane = threadIdx.x & 63;
    int lo = rowptr[d];     if (lo < jb)   lo = jb;
    int hi = rowptr[d + 1]; if (hi > jend) hi = jend;
    if (lo >= hi) return;
    float4 accS = {0.f, 0.f, 0.f, 0.f};
    float4 accG = {0.f, 0.f, 0.f, 0.f};
    for (int j = lo; j < hi; ++j) {
        int e  = col[j];
        int si = ei[e];
        float4 s = ld_bf4(Psrc + (size_t)si * CD + lane * 4);
        float4 g = ld_bf4(G + (size_t)(j - jb) * CD + lane * 4);
        accS.x += g.x * s.x; accS.y += g.y * s.y; accS.z += g.z * s.z; accS.w += g.w * s.w;
        accG.x += g.x; accG.y += g.y; accG.z += g.z; accG.w += g.w;
    }
    float4 dv = ld_bf4(Pdst + (size_t)d * CD + lane * 4);
    float* ap = aggr + (size_t)d * CD + lane * 4;
    atomicAdd(ap + 0, accS.x + accG.x * dv.x);
    atomicAdd(ap + 1, accS.y + accG.y * dv.y);
    atomicAdd(ap + 2, accS.z + accG.z * dv.z);
    atomicAdd(ap + 3, accS.w + accG.w * dv.w);
}

// ---------------------------------------------------------------------------
extern "C" void kernel_launch(void* const* d_in, const int* in_sizes, int n_in,
                              void* d_out, int out_size, void* d_ws, size_t ws_size,
                              hipStream_t stream)
{
    const float* x_chem = (const float*)d_in[0];
    const float* x_gene = (const float*)d_in[1];
    const float* x_go   = (const float*)d_in[2];
    const float* x_pw   = (const float*)d_in[3];
    const int*   ei_cg  = (const int*)d_in[4];
    const int*   ei_cp  = (const int*)d_in[5];
    const int*   ei_ce  = (const int*)d_in[6];
    const int*   ei_gg  = (const int*)d_in[7];
    const int*   ea_cg  = (const int*)d_in[8];
    const int*   ea_cp  = (const int*)d_in[9];
    const float* ea_ce  = (const float*)d_in[10];

    const float* W_src_cg = (const float*)d_in[11];
    const float* b_src_cg = (const float*)d_in[12];
    const float* W_dst_cg = (const float*)d_in[13];
    const float* b_dst_cg = (const float*)d_in[14];
    const float* W_src_cp = (const float*)d_in[16];
    const float* b_src_cp = (const float*)d_in[17];
    const float* W_dst_cp = (const float*)d_in[18];
    const float* b_dst_cp = (const float*)d_in[19];
    const float* W_src_ce = (const float*)d_in[21];
    const float* b_src_ce = (const float*)d_in[22];
    const float* W_dst_ce = (const float*)d_in[23];
    const float* b_dst_ce = (const float*)d_in[24];
    const float* W_src_gg = (const float*)d_in[26];
    const float* b_src_gg = (const float*)d_in[27];
    const float* W_dst_gg = (const float*)d_in[28];
    const float* b_dst_gg = (const float*)d_in[29];

    const float* emb_at   = (const float*)d_in[31];
    const float* emb_as   = (const float*)d_in[32];
    const float* W_gate_cg = (const float*)d_in[33];
    const float* b_gate_cg = (const float*)d_in[34];
    const float* emb_ph   = (const float*)d_in[35];
    const float* W_gate_cp = (const float*)d_in[36];
    const float* b_gate_cp = (const float*)d_in[37];
    const float* W_gate1_ce = (const float*)d_in[38];
    const float* b_gate1_ce = (const float*)d_in[39];
    const float* W_gate2_ce = (const float*)d_in[40];
    const float* b_gate2_ce = (const float*)d_in[41];
    const float* W_out_gene = (const float*)d_in[42];
    const float* b_out_gene = (const float*)d_in[43];
    const float* W_out_go   = (const float*)d_in[44];
    const float* b_out_go   = (const float*)d_in[45];
    const float* W_out_pw   = (const float*)d_in[46];
    const float* b_out_pw   = (const float*)d_in[47];

    const int Nc  = in_sizes[0] / CD;
    const int Ng  = in_sizes[1] / CD;
    const int Ngo = in_sizes[2] / CD;
    const int Np  = in_sizes[3] / CD;
    const int E   = in_sizes[4] / 2;

    // ---- workspace layout (float units; fixed total ~85 MB) ----
    float* ws = (float*)d_ws;
    size_t off = 0;
    float* aggr_gene = ws + off; off += (size_t)Ng  * CD;
    float* aggr_go   = ws + off; off += (size_t)Ngo * CD;
    float* aggr_pw   = ws + off; off += (size_t)Np  * CD;   // aggr_* contiguous
    int maxSrc = (Nc > Ng) ? Nc : Ng;
    int maxDst = Ng; if (Ngo > maxDst) maxDst = Ngo; if (Np > maxDst) maxDst = Np;
    u16* projb_src = (u16*)(ws + off); off += (size_t)maxSrc * CD / 2;
    u16* projb_dst = (u16*)(ws + off); off += (size_t)maxDst * CD / 2;
    u16* wt_all    = (u16*)(ws + off); off += (size_t)12 * CD * CD / 2;
    float* gtab_cg = ws + off; off += 50 * CD;
    float* gtab_cp = ws + off; off += 3 * CD;
    // CSR ints
    int* deg    = (int*)(ws + off);
    int* cursor = deg + (maxDst + 1);
    int* rowptr = cursor + (maxDst + 1);
    int* colv   = rowptr + (maxDst + 2);
    {
        size_t ints = 2 * (size_t)(maxDst + 1) + (size_t)(maxDst + 2) + (size_t)E;
        off += (ints + 3) & ~(size_t)3;
    }
    // remaining -> bf16 ce gate buffer (CSR-ordered); one row = 128 floats.
    // SIGNED arithmetic + clamps: never exceed the workspace.
    u16* gate_ce = (u16*)(ws + off);
    long long remaining = (long long)(ws_size / 4) - (long long)off;
    if (remaining < 0) remaining = 0;
    long long CHUNKll = remaining / 128;
    if (CHUNKll > 32000) CHUNKll = 32000;
    if (CHUNKll > E) CHUNKll = E;
    int CHUNK = (int)CHUNKll;
    if (CHUNK < 1) CHUNK = 1;

    float* out_gene = (float*)d_out + (size_t)Nc * CD;
    float* out_go   = out_gene + (size_t)Ng * CD;
    float* out_pw   = out_go + (size_t)Ngo * CD;

    const int EB = (E + 255) / 256;

    auto gemm_bf = [&](const float* A, const u16* Wt, const float* b, u16* Y, int N) {
        gemm_mfma<1><<<(N + 63) / 64, 256, 0, stream>>>(A, Wt, b, nullptr, Y, N, 1.0f);
    };
    auto gemm_f = [&](const float* A, const u16* Wt, const float* b, float* Y, int N, float alpha) {
        gemm_mfma<0><<<(N + 63) / 64, 256, 0, stream>>>(A, Wt, b, Y, nullptr, N, alpha);
    };
    // BUG FIX (r4): cursor lives at deg+(maxDst+1); the fused memset
    // 2*(n_dst+1) only covered cursor when n_dst==maxDst (cg/gg). For cp/ce
    // the cursor kept stale cg-pass values -> scatter_k shifted every row's
    // edges -> out_go/out_pw off by O(few messages). Memset each array at
    // its true location.
    auto build_csr = [&](const int* ei, int n_dst) {
        hipMemsetAsync(deg,    0, (size_t)(n_dst + 1) * sizeof(int), stream);
        hipMemsetAsync(cursor, 0, (size_t)(n_dst + 1) * sizeof(int), stream);
        hist_k<<<EB, 256, 0, stream>>>(ei, E, deg);
        exscan_k<<<1, 1024, 0, stream>>>(deg, rowptr, n_dst);
        scatter_k<<<EB, 256, 0, stream>>>(ei, E, rowptr, cursor, colv);
    };

    // 1) passthrough copy
    hipMemcpyAsync(d_out, x_chem, (size_t)Nc * CD * sizeof(float),
                   hipMemcpyDeviceToDevice, stream);

    // 2) weight transpose+convert (12 C x C matrices -> bf16 Wt[n][k])
    u16* Wt_src_cg = wt_all + 0 * CD * CD;  u16* Wt_dst_cg = wt_all + 1 * CD * CD;
    u16* Wt_src_cp = wt_all + 2 * CD * CD;  u16* Wt_dst_cp = wt_all + 3 * CD * CD;
    u16* Wt_src_ce = wt_all + 4 * CD * CD;  u16* Wt_dst_ce = wt_all + 5 * CD * CD;
    u16* Wt_src_gg = wt_all + 6 * CD * CD;  u16* Wt_dst_gg = wt_all + 7 * CD * CD;
    u16* Wt_g2_ce  = wt_all + 8 * CD * CD;
    u16* Wt_o_gene = wt_all + 9 * CD * CD;  u16* Wt_o_go = wt_all + 10 * CD * CD;
    u16* Wt_o_pw   = wt_all + 11 * CD * CD;
    {
        WtArgs wa;
        const float* s[12] = {W_src_cg, W_dst_cg, W_src_cp, W_dst_cp, W_src_ce, W_dst_ce,
                              W_src_gg, W_dst_gg, W_gate2_ce, W_out_gene, W_out_go, W_out_pw};
        u16* dpt[12] = {Wt_src_cg, Wt_dst_cg, Wt_src_cp, Wt_dst_cp, Wt_src_ce, Wt_dst_ce,
                        Wt_src_gg, Wt_dst_gg, Wt_g2_ce, Wt_o_gene, Wt_o_go, Wt_o_pw};
        for (int i = 0; i < 12; ++i) { wa.src[i] = s[i]; wa.dst[i] = dpt[i]; }
        wtrans_k<<<dim3(16, 12), 256, 0, stream>>>(wa);
    }

    // 3) gate tables
    gate_cg_table_k<<<50, 256, 0, stream>>>(emb_at, emb_as, W_gate_cg, b_gate_cg, gtab_cg);
    gate_cp_table_k<<<3, 256, 0, stream>>>(emb_ph, W_gate_cp, b_gate_cp, gtab_cp);

    // 4) cg: chemical -> gene (store into aggr_gene)
    gemm_bf(x_chem, Wt_src_cg, b_src_cg, projb_src, Nc);
    gemm_bf(x_gene, Wt_dst_cg, b_dst_cg, projb_dst, Ng);
    build_csr(ei_cg, Ng);
    dest_aggr<1, 0><<<(Ng + 3) / 4, 256, 0, stream>>>(projb_src, projb_dst, ei_cg, E,
                                                      rowptr, colv, gtab_cg, ea_cg,
                                                      aggr_gene, Ng);

    // 5) cp: chemical -> go_term
    gemm_bf(x_chem, Wt_src_cp, b_src_cp, projb_src, Nc);
    gemm_bf(x_go,   Wt_dst_cp, b_dst_cp, projb_dst, Ngo);
    build_csr(ei_cp, Ngo);
    dest_aggr<2, 0><<<(Ngo + 3) / 4, 256, 0, stream>>>(projb_src, projb_dst, ei_cp, E,
                                                       rowptr, colv, gtab_cp, ea_cp,
                                                       aggr_go, Ngo);

    // 6) ce: chemical -> pathway (continuous gate, CSR-ordered bf16 chunks)
    gemm_bf(x_chem, Wt_src_ce, b_src_ce, projb_src, Nc);
    gemm_bf(x_pw,   Wt_dst_ce, b_dst_ce, projb_dst, Np);
    build_csr(ei_ce, Np);
    hipMemsetAsync(aggr_pw, 0, (size_t)Np * CD * sizeof(float), stream);
    for (int jb = 0; jb < E; jb += CHUNK) {
        int cnt = E - jb; if (cnt > CHUNK) cnt = CHUNK;
        gate_ce_mfma<<<(cnt + 63) / 64, 256, 0, stream>>>(ea_ce, colv, W_gate1_ce, b_gate1_ce,
                                                          Wt_g2_ce, b_gate2_ce, gate_ce, jb, cnt);
        ce_aggr_chunk<<<(Np + 3) / 4, 256, 0, stream>>>(projb_src, projb_dst, ei_ce, E,
                                                        rowptr, colv, gate_ce,
                                                        aggr_pw, Np, jb, jb + cnt);
    }

    // 7) gg: gene -> gene (no gate), read-add-store into aggr_gene
    gemm_bf(x_gene, Wt_src_gg, b_src_gg, projb_src, Ng);
    gemm_bf(x_gene, Wt_dst_gg, b_dst_gg, projb_dst, Ng);
    build_csr(ei_gg, Ng);
    dest_aggr<0, 1><<<(Ng + 3) / 4, 256, 0, stream>>>(projb_src, projb_dst, ei_gg, E,
                                                      rowptr, colv, nullptr, nullptr,
                                                      aggr_gene, Ng);

    // 8) output heads straight from fp32 aggr (alpha folds attention 0.25; gene
    //    branch additionally has the 0.5 from 0.5*(aggr_cg+aggr_gg))
    gemm_f(aggr_gene, Wt_o_gene, b_out_gene, out_gene, Ng,  0.125f);
    gemm_f(aggr_go,   Wt_o_go,   b_out_go,   out_go,   Ngo, 0.25f);
    gemm_f(aggr_pw,   Wt_o_pw,   b_out_pw,   out_pw,   Np,  0.25f);
}